// Round 1
// baseline (1037.215 us; speedup 1.0000x reference)
//
#include <hip/hip_runtime.h>
#include <math.h>

// ---------------------------------------------------------------------------
// xqdaLoss: loss, dist, norm_i, norm_j from pairwise covariance statistics.
//
// Algebra (t = target, c_k = class count, g_k = class column-sum, s = total
// column sum, T = X^T X, P = X^T diag(c_{t_i}) X, G = sum_k g_k g_k^T):
//   cov_pos = P - G
//   cov_neg = N*T - P - s s^T + G
//   vec_pos = X^T a,  a_i = 2*r_i - c_{t_i} + 1      (r_i = rank within class)
//   vec_neg = X^T b,  b_i = 2*i - 2*r_i + c_{t_i} - N
//   npos    = sum_k c_k (c_k - 1)/2, nneg = N(N-1)/2 - npos
// Only Frobenius norms are needed -> accumulate sums of squares, never
// materialize the CxC matrices.
// ---------------------------------------------------------------------------

#define TI 64   // output tile (TI x TI per block)
#define CH 64   // rows staged per chunk
#define NUM_K 256

// --- class sums + counts: one block per class ------------------------------
__global__ void k_classum(const float* __restrict__ x, const int* __restrict__ t,
                          float* __restrict__ g, int* __restrict__ counts,
                          int N, int C) {
    int k = blockIdx.x;
    int tid = threadIdx.x;
    const int per = 8;                      // C / 256
    float acc[per];
#pragma unroll
    for (int j = 0; j < per; ++j) acc[j] = 0.f;
    int cnt = 0;
    for (int i = 0; i < N; ++i) {
        if (t[i] == k) {
            ++cnt;
            const float* row = x + (size_t)i * C;
#pragma unroll
            for (int j = 0; j < per; ++j) acc[j] += row[tid + j * 256];
        }
    }
#pragma unroll
    for (int j = 0; j < per; ++j) g[(size_t)k * C + tid + j * 256] = acc[j];
    if (tid == 0) counts[k] = cnt;
}

// --- column totals s_c = sum_k g[k][c] -------------------------------------
__global__ void k_colsum(const float* __restrict__ g, float* __restrict__ s,
                         int C, int K) {
    int c = blockIdx.x * blockDim.x + threadIdx.x;
    if (c >= C) return;
    float acc = 0.f;
    for (int k = 0; k < K; ++k) acc += g[(size_t)k * C + c];
    s[c] = acc;
}

// --- per-row coefficients a_i, b_i and weight w_i = c_{t_i} ----------------
__global__ void k_coeff(const int* __restrict__ t, const int* __restrict__ counts,
                        float* __restrict__ ca, float* __restrict__ cb,
                        float* __restrict__ wr, int N) {
    int i = blockIdx.x * blockDim.x + threadIdx.x;
    if (i >= N) return;
    int ti = t[i];
    int r = 0;
    for (int j = 0; j < i; ++j) r += (t[j] == ti) ? 1 : 0;
    int c = counts[ti];
    ca[i] = (float)(2 * r - c + 1);
    cb[i] = (float)(2 * i - 2 * r + c - N);
    wr[i] = (float)c;
}

// --- vec_pos / vec_neg (X^T a, X^T b) with row-chunked atomics -------------
__global__ void k_vec(const float* __restrict__ x, const float* __restrict__ ca,
                      const float* __restrict__ cb, float* __restrict__ vp,
                      float* __restrict__ vn, int N, int C) {
    int c = blockIdx.x * blockDim.x + threadIdx.x;
    int i0 = blockIdx.y * 256;
    float ap = 0.f, an = 0.f;
    for (int i = i0; i < i0 + 256; ++i) {
        float xv = x[(size_t)i * C + c];
        ap = fmaf(ca[i], xv, ap);
        an = fmaf(cb[i], xv, an);
    }
    atomicAdd(vp + c, ap);
    atomicAdd(vn + c, an);
}

// --- main tile kernel: T, P, G on a TIxTI tile; reduce Frobenius partials --
__global__ __launch_bounds__(256) void k_tile(
    const float* __restrict__ x, const float* __restrict__ g,
    const float* __restrict__ s, const float* __restrict__ wr,
    float* __restrict__ ssq, int N, int C, int K) {
    // decode triangular tile index (bi <= bj)
    int nt = C / TI;
    int b = blockIdx.x;
    int bi = 0, rem = b;
    while (rem >= nt - bi) { rem -= nt - bi; ++bi; }
    int bj = bi + rem;

    __shared__ float As[CH][TI];
    __shared__ float Aw[CH][TI];
    __shared__ float Bs[CH][TI];

    int tid = threadIdx.x;
    int tx = tid & 15, ty = tid >> 4;

    float tacc[4][4] = {{0}}, pacc[4][4] = {{0}}, gacc[4][4] = {{0}};

    // ---- accumulate T (plain Gram) and P (weighted Gram) over N rows ----
    for (int i0 = 0; i0 < N; i0 += CH) {
        __syncthreads();
        for (int l = tid; l < CH * (TI / 4); l += 256) {
            int r = l >> 4;
            int c4 = l & 15;
            int row = i0 + r;
            float w = wr[row];
            const float4 va = *(const float4*)(x + (size_t)row * C + bi * TI + c4 * 4);
            const float4 vb = *(const float4*)(x + (size_t)row * C + bj * TI + c4 * 4);
            *(float4*)&As[r][c4 * 4] = va;
            float4 vw;
            vw.x = va.x * w; vw.y = va.y * w; vw.z = va.z * w; vw.w = va.w * w;
            *(float4*)&Aw[r][c4 * 4] = vw;
            *(float4*)&Bs[r][c4 * 4] = vb;
        }
        __syncthreads();
#pragma unroll 4
        for (int kk = 0; kk < CH; ++kk) {
            float av[4], aw[4], bv[4];
            *(float4*)av = *(const float4*)&As[kk][ty * 4];
            *(float4*)aw = *(const float4*)&Aw[kk][ty * 4];
            *(float4*)bv = *(const float4*)&Bs[kk][tx * 4];
#pragma unroll
            for (int i = 0; i < 4; ++i)
#pragma unroll
                for (int j = 0; j < 4; ++j) {
                    tacc[i][j] = fmaf(av[i], bv[j], tacc[i][j]);
                    pacc[i][j] = fmaf(aw[i], bv[j], pacc[i][j]);
                }
        }
    }

    // ---- accumulate G = sum_k g_k g_k^T over K class rows ----
    for (int k0 = 0; k0 < K; k0 += CH) {
        __syncthreads();
        for (int l = tid; l < CH * (TI / 4); l += 256) {
            int r = l >> 4;
            int c4 = l & 15;
            int row = k0 + r;
            *(float4*)&As[r][c4 * 4] = *(const float4*)(g + (size_t)row * C + bi * TI + c4 * 4);
            *(float4*)&Bs[r][c4 * 4] = *(const float4*)(g + (size_t)row * C + bj * TI + c4 * 4);
        }
        __syncthreads();
#pragma unroll 4
        for (int kk = 0; kk < CH; ++kk) {
            float av[4], bv[4];
            *(float4*)av = *(const float4*)&As[kk][ty * 4];
            *(float4*)bv = *(const float4*)&Bs[kk][tx * 4];
#pragma unroll
            for (int i = 0; i < 4; ++i)
#pragma unroll
                for (int j = 0; j < 4; ++j)
                    gacc[i][j] = fmaf(av[i], bv[j], gacc[i][j]);
        }
    }

    // ---- combine into Frobenius partial sums ----
    float sA[4], sB[4];
#pragma unroll
    for (int i = 0; i < 4; ++i) sA[i] = s[bi * TI + ty * 4 + i];
#pragma unroll
    for (int j = 0; j < 4; ++j) sB[j] = s[bj * TI + tx * 4 + j];
    float fac = (bi == bj) ? 1.f : 2.f;  // off-diagonal tiles appear twice
    float fN = (float)N;
    float la = 0.f, lb = 0.f, ld = 0.f;
#pragma unroll
    for (int i = 0; i < 4; ++i)
#pragma unroll
        for (int j = 0; j < 4; ++j) {
            float A = pacc[i][j] - gacc[i][j];
            float B = fN * tacc[i][j] - pacc[i][j] - sA[i] * sB[j] + gacc[i][j];
            float D = A - B;
            la += A * A;
            lb += B * B;
            ld += D * D;
        }
    la *= fac; lb *= fac; ld *= fac;

    // ---- block reduce (reuse As as scratch) ----
    __syncthreads();
    float* red = &As[0][0];
    red[tid] = la;
    red[256 + tid] = lb;
    red[512 + tid] = ld;
    __syncthreads();
    for (int off = 128; off > 0; off >>= 1) {
        if (tid < off) {
            red[tid] += red[tid + off];
            red[256 + tid] += red[256 + tid + off];
            red[512 + tid] += red[512 + tid + off];
        }
        __syncthreads();
    }
    if (tid == 0) {
        atomicAdd(ssq + 0, red[0]);
        atomicAdd(ssq + 1, red[256]);
        atomicAdd(ssq + 2, red[512]);
    }
}

// --- final: npos/nneg, mean-vector norm, outputs ---------------------------
__global__ void k_final(const float* __restrict__ vp, const float* __restrict__ vn,
                        const int* __restrict__ counts, const float* __restrict__ ssq,
                        const int* __restrict__ hyper, const int* __restrict__ usemean,
                        const int* __restrict__ use_exp, float* __restrict__ out,
                        int N, int C, int K) {
    __shared__ float red[256];
    __shared__ float rnp[256];
    int tid = threadIdx.x;
    float np_part = 0.f;
    if (tid < K) {
        float ck = (float)counts[tid];
        np_part = ck * (ck - 1.f) * 0.5f;
    }
    rnp[tid] = np_part;
    __syncthreads();
    for (int off = 128; off > 0; off >>= 1) {
        if (tid < off) rnp[tid] += rnp[tid + off];
        __syncthreads();
    }
    float npos = rnp[0];
    float nneg = 0.5f * (float)N * ((float)N - 1.f) - npos;

    float acc = 0.f;
    for (int c = tid; c < C; c += 256) {
        float u = vp[c] / npos - vn[c] / nneg;
        acc += u * u;
    }
    red[tid] = acc;
    __syncthreads();
    for (int off = 128; off > 0; off >>= 1) {
        if (tid < off) red[tid] += red[tid + off];
        __syncthreads();
    }
    if (tid == 0) {
        float norm_i = sqrtf(ssq[0]);
        float norm_j = sqrtf(ssq[1]);
        float h = (float)hyper[0];
        float um = (float)usemean[0];
        float loss, dist;
        if (use_exp[0] != 0) {
            dist = expf(-sqrtf(ssq[2]));
            loss = dist;
        } else {
            float mean_norm = sqrtf((float)C) * sqrtf(red[0]);
            dist = norm_i - h * norm_j - um * mean_norm;
            loss = fmaxf(dist, 0.f);
        }
        out[0] = loss;
        out[1] = dist;
        out[2] = norm_i;
        out[3] = norm_j;
    }
}

extern "C" void kernel_launch(void* const* d_in, const int* in_sizes, int n_in,
                              void* d_out, int out_size, void* d_ws, size_t ws_size,
                              hipStream_t stream) {
    const float* x = (const float*)d_in[0];
    const int* t = (const int*)d_in[1];
    const int* hyper = (const int*)d_in[2];
    const int* usemean = (const int*)d_in[3];
    const int* use_exp = (const int*)d_in[4];
    float* out = (float*)d_out;

    int N = in_sizes[1];
    int C = in_sizes[0] / N;
    const int K = NUM_K;

    // workspace layout
    char* ws = (char*)d_ws;
    int* counts = (int*)ws;                       // 256 ints
    float* g = (float*)(ws + 1024);               // K * C
    float* s = g + (size_t)K * C;                 // C
    float* ca = s + C;                            // N
    float* cb = ca + N;                           // N
    float* wr = cb + N;                           // N
    float* vp = wr + N;                           // C
    float* vn = vp + C;                           // C
    float* ssq = vn + C;                          // 4

    // zero only atomically-accumulated regions (vp, vn, ssq are contiguous)
    hipMemsetAsync(vp, 0, (size_t)(2 * C + 4) * sizeof(float), stream);

    k_classum<<<K, 256, 0, stream>>>(x, t, g, counts, N, C);
    k_colsum<<<(C + 255) / 256, 256, 0, stream>>>(g, s, C, K);
    k_coeff<<<(N + 255) / 256, 256, 0, stream>>>(t, counts, ca, cb, wr, N);
    k_vec<<<dim3(C / 256, N / 256), 256, 0, stream>>>(x, ca, cb, vp, vn, N, C);

    int nt = C / TI;
    k_tile<<<nt * (nt + 1) / 2, 256, 0, stream>>>(x, g, s, wr, ssq, N, C, K);

    k_final<<<1, 256, 0, stream>>>(vp, vn, counts, ssq, hyper, usemean, use_exp,
                                   out, N, C, K);
}

// Round 2
// 456.725 us; speedup vs baseline: 2.2710x; 2.2710x over previous
//
#include <hip/hip_runtime.h>
#include <math.h>

// ---------------------------------------------------------------------------
// xqdaLoss via the N-side Gram. With K = X X^T, Z = class indicator, M = ZZ^T,
// D = diag(c_{t_i}), s = X^T 1, g = Z^T X:
//   T = X^T X, P = X^T D X, G = X^T M X  (never materialized)
//   ||T||^2 = Sum K^2, tr(TP) = Sum d_i K^2, ||P||^2 = Sum d_i d_j K^2
//   tr(TG) = ||X g^T||^2, tr(PG) = Sum_i d_i (X g^T)_i^2, ||G||^2 = ||g g^T||^2
//   s^T T s = ||X s||^2, s^T P s = Sum d_i (Xs)_i^2, s^T G s = Sum_a (g_a . s)^2
// All produced by ONE symmetric bf16 MFMA Gram of A_ext = [X; g; s; 0-pad]
// (4480 x 2048) with a region-aware epilogue -> 10 scalars.
// ---------------------------------------------------------------------------

#define N_ROWS 4096
#define C_DIM  2048
#define NCLS   256
#define RLCAP  64
#define NT     35      // extended 128-row blocks: 32 X + 2 g + 1 (s + pad)
#define NKC    32      // C / 64
#define TILE_E 8192    // 128 rows * 64 cols
#define TILE_B 16384   // bytes (bf16)

typedef __attribute__((ext_vector_type(8))) short short8v;
typedef __attribute__((ext_vector_type(4))) float f32x4;

__device__ __forceinline__ unsigned short f2bf(float f) {
    unsigned u = __float_as_uint(f);
    u += 0x7FFF + ((u >> 16) & 1);   // round-to-nearest-even
    return (unsigned short)(u >> 16);
}

__device__ __forceinline__ void gload16(const void* g, void* l) {
    __builtin_amdgcn_global_load_lds(
        (const __attribute__((address_space(1))) unsigned int*)g,
        (__attribute__((address_space(3))) unsigned int*)l, 16, 0, 0);
}

// swizzled tile byte offset of element (r, c), c in [0,64): 16B-slot XOR
__device__ __forceinline__ int swz_off(int r, int c8) {
    return r * 128 + ((c8 ^ (r & 7)) << 4);
}

// --- class scan: counts, row lists, per-row coefficients -------------------
__global__ void k_scan(const int* __restrict__ t, int* __restrict__ counts,
                       int* __restrict__ rowlist, float* __restrict__ ca,
                       float* __restrict__ cb, float* __restrict__ dr) {
    __shared__ int ts[N_ROWS];
    for (int i = threadIdx.x; i < N_ROWS; i += 256) ts[i] = t[i];
    __syncthreads();
    int a = threadIdx.x;                 // class id
    int cnt = 0;
    for (int i = 0; i < N_ROWS; ++i) {
        if (ts[i] == a) {
            if (cnt < RLCAP) rowlist[a * RLCAP + cnt] = i;
            ++cnt;
        }
    }
    counts[a] = cnt;
    int cc = cnt < RLCAP ? cnt : RLCAP;
    for (int r = 0; r < cc; ++r) {
        int i = rowlist[a * RLCAP + r];
        ca[i] = (float)(2 * r - cnt + 1);
        cb[i] = (float)(2 * i - 2 * r + cnt - N_ROWS);
        dr[i] = (float)cnt;
    }
}

// --- class column-sums g[a][c] (uses row lists) ----------------------------
__global__ void k_classum(const float* __restrict__ x, const int* __restrict__ counts,
                          const int* __restrict__ rowlist, float* __restrict__ g) {
    int a = blockIdx.x, tid = threadIdx.x;
    int cnt = counts[a]; if (cnt > RLCAP) cnt = RLCAP;
    float a0=0,a1=0,a2=0,a3=0,a4=0,a5=0,a6=0,a7=0;
    for (int r = 0; r < cnt; ++r) {
        const float* row = x + (size_t)rowlist[a * RLCAP + r] * C_DIM;
        float4 v0 = *(const float4*)(row + tid * 4);
        float4 v1 = *(const float4*)(row + 1024 + tid * 4);
        a0+=v0.x; a1+=v0.y; a2+=v0.z; a3+=v0.w;
        a4+=v1.x; a5+=v1.y; a6+=v1.z; a7+=v1.w;
    }
    float* go = g + (size_t)a * C_DIM;
    *(float4*)(go + tid * 4) = make_float4(a0,a1,a2,a3);
    *(float4*)(go + 1024 + tid * 4) = make_float4(a4,a5,a6,a7);
}

// --- column totals s_c -----------------------------------------------------
__global__ void k_colsum(const float* __restrict__ g, float* __restrict__ s,
                         int C, int K) {
    int c = blockIdx.x * blockDim.x + threadIdx.x;
    if (c >= C) return;
    float acc = 0.f;
    for (int k = 0; k < K; ++k) acc += g[(size_t)k * C + c];
    s[c] = acc;
}

// --- convert X -> tiled, swizzled bf16 (row blocks 0..31) ------------------
__global__ void k_conv_x(const float* __restrict__ x, unsigned char* __restrict__ xbf) {
    int rb = blockIdx.x >> 5;
    int kc = blockIdx.x & 31;
    unsigned char* tile = xbf + (size_t)(rb * NKC + kc) * TILE_B;
    int t = threadIdx.x;
    int r = t >> 1;
    int half = t & 1;
    const float* src = x + (size_t)(rb * 128 + r) * C_DIM + kc * 64;
#pragma unroll
    for (int u = 0; u < 4; ++u) {
        int c8 = half * 4 + u;
        const float4 v0 = *(const float4*)(src + c8 * 8);
        const float4 v1 = *(const float4*)(src + c8 * 8 + 4);
        int4 w;
        w.x = (int)(f2bf(v0.x) | ((unsigned)f2bf(v0.y) << 16));
        w.y = (int)(f2bf(v0.z) | ((unsigned)f2bf(v0.w) << 16));
        w.z = (int)(f2bf(v1.x) | ((unsigned)f2bf(v1.y) << 16));
        w.w = (int)(f2bf(v1.z) | ((unsigned)f2bf(v1.w) << 16));
        *(int4*)(tile + swz_off(r, c8)) = w;
    }
}

// --- convert extension rows (g, s, zero pad) -> row blocks 32..34 ----------
__global__ void k_conv_ext(const float* __restrict__ g, const float* __restrict__ s,
                           unsigned char* __restrict__ xbf) {
    int bx = blockIdx.x;                 // 0..95
    int rb = 32 + (bx >> 5);
    int kc = bx & 31;
    unsigned char* tile = xbf + (size_t)(rb * NKC + kc) * TILE_B;
    int t = threadIdx.x;
    int r = t >> 1;
    int half = t & 1;
    int grow = rb * 128 + r - N_ROWS;    // 0..383
    const float* src = nullptr;
    if (grow < NCLS)        src = g + (size_t)grow * C_DIM + kc * 64;
    else if (grow == NCLS)  src = s + kc * 64;
#pragma unroll
    for (int u = 0; u < 4; ++u) {
        int c8 = half * 4 + u;
        int4 w = make_int4(0, 0, 0, 0);
        if (src) {
            const float4 v0 = *(const float4*)(src + c8 * 8);
            const float4 v1 = *(const float4*)(src + c8 * 8 + 4);
            w.x = (int)(f2bf(v0.x) | ((unsigned)f2bf(v0.y) << 16));
            w.y = (int)(f2bf(v0.z) | ((unsigned)f2bf(v0.w) << 16));
            w.z = (int)(f2bf(v1.x) | ((unsigned)f2bf(v1.y) << 16));
            w.w = (int)(f2bf(v1.z) | ((unsigned)f2bf(v1.w) << 16));
        }
        *(int4*)(tile + swz_off(r, c8)) = w;
    }
}

// --- vec_pos / vec_neg (X^T a, X^T b) --------------------------------------
__global__ void k_vec(const float* __restrict__ x, const float* __restrict__ ca,
                      const float* __restrict__ cb, float* __restrict__ vp,
                      float* __restrict__ vn, int N, int C) {
    int c = blockIdx.x * blockDim.x + threadIdx.x;
    int i0 = blockIdx.y * 256;
    float ap = 0.f, an = 0.f;
    for (int i = i0; i < i0 + 256; ++i) {
        float xv = x[(size_t)i * C + c];
        ap = fmaf(ca[i], xv, ap);
        an = fmaf(cb[i], xv, an);
    }
    atomicAdd(vp + c, ap);
    atomicAdd(vn + c, an);
}

// --- fragment load: row-major swizzled bf16 tile, both A and B operands ----
__device__ __forceinline__ short8v frag_load(const unsigned char* buf, int rowbase,
                                             int kg, int lane) {
    int row = rowbase + (lane & 15);
    int kgroup = kg + (lane >> 4);
    return *(const short8v*)(buf + row * 128 + (((kgroup ^ (row & 7)) << 4)));
}

// --- extended Gram: MFMA over 128x128 tiles, region-aware epilogue ---------
__global__ __launch_bounds__(256) void k_gram(
    const unsigned char* __restrict__ xbf, const float* __restrict__ dr,
    float* __restrict__ ssq) {
    int b = blockIdx.x, bi = 0;
    while (b >= NT - bi) { b -= NT - bi; ++bi; }
    int bj = bi + b;
    bool diag = (bi == bj);

    __shared__ __align__(16) unsigned char Abuf[TILE_B];
    __shared__ __align__(16) unsigned char Bbuf[TILE_B];
    __shared__ float drow[128], dcol[128];
    __shared__ float wred[4 * 16];

    int tid = threadIdx.x;
    int lane = tid & 63;
    int w = tid >> 6;
    int wr = (w >> 1) * 64;
    int wc = (w & 1) * 64;

    if (tid < 128) {
        int gi = bi * 128 + tid;
        drow[tid] = (gi < N_ROWS) ? dr[gi] : 0.f;
        int gj = bj * 128 + tid;
        dcol[tid] = (gj < N_ROWS) ? dr[gj] : 0.f;
    }

    f32x4 acc[4][4] = {};

    const unsigned char* abase = xbf + (size_t)bi * NKC * TILE_B;
    const unsigned char* bbase = xbf + (size_t)bj * NKC * TILE_B;

    for (int kc = 0; kc < NKC; ++kc) {
        const unsigned char* at = abase + (size_t)kc * TILE_B;
#pragma unroll
        for (int u = 0; u < 4; ++u) {
            int inst = (w << 2) + u;
            gload16(at + inst * 1024 + lane * 16, Abuf + inst * 1024);
        }
        if (!diag) {
            const unsigned char* bt = bbase + (size_t)kc * TILE_B;
#pragma unroll
            for (int u = 0; u < 4; ++u) {
                int inst = (w << 2) + u;
                gload16(bt + inst * 1024 + lane * 16, Bbuf + inst * 1024);
            }
        }
        __syncthreads();
        const unsigned char* bb = diag ? Abuf : Bbuf;
        short8v a[4][2], bfm[4][2];
#pragma unroll
        for (int m = 0; m < 4; ++m)
#pragma unroll
            for (int h = 0; h < 2; ++h) {
                a[m][h]   = frag_load(Abuf, wr + m * 16, h * 4, lane);
                bfm[m][h] = frag_load(bb,   wc + m * 16, h * 4, lane);
            }
#pragma unroll
        for (int m = 0; m < 4; ++m)
#pragma unroll
            for (int n = 0; n < 4; ++n) {
#pragma unroll
                for (int h = 0; h < 2; ++h)
                    acc[m][n] = __builtin_amdgcn_mfma_f32_16x16x32_bf16(
                        a[m][h], bfm[n][h], acc[m][n], 0, 0, 0);
            }
        __syncthreads();
    }

    // epilogue: region-classified weighted square-sums
    float fK = diag ? 1.f : 2.f;
    float vs[10] = {0,0,0,0,0,0,0,0,0,0};
#pragma unroll
    for (int m = 0; m < 4; ++m) {
#pragma unroll
        for (int q = 0; q < 4; ++q) {
            int iw = wr + m * 16 + (lane >> 4) * 4 + q;
            int gi = bi * 128 + iw;
            float di = drow[iw];
            bool iX = gi < N_ROWS;
            bool iG = !iX && (gi < N_ROWS + NCLS);
            bool iS = gi == N_ROWS + NCLS;
#pragma unroll
            for (int n = 0; n < 4; ++n) {
                int jw = wc + n * 16 + (lane & 15);
                int gj = bj * 128 + jw;
                float dj = dcol[jw];
                float k = acc[m][n][q];
                float k2 = k * k;
                bool jX = gj < N_ROWS;
                bool jG = !jX && (gj < N_ROWS + NCLS);
                bool jS = gj == N_ROWS + NCLS;
                if (iX && jX) {
                    vs[0] += fK * k2;                        // Sum K^2
                    vs[1] += 0.5f * fK * (di + dj) * k2;     // Sum d_i K^2
                    vs[2] += fK * di * dj * k2;              // Sum d_i d_j K^2
                } else if (iX && jG) {
                    vs[3] += k2;                             // ||R||^2 = tr(TG)
                    vs[4] += di * k2;                        // tr(PG)
                } else if (iX && jS) {
                    vs[6] += k2;                             // s^T T s
                    vs[7] += di * k2;                        // s^T P s
                } else if (iG && jG) {
                    vs[5] += fK * k2;                        // ||Q||^2 = ||G||^2
                } else if (iG && jS) {
                    vs[8] += k2;                             // s^T G s
                } else if (iS && jS) {
                    vs[9] += k;                              // s^T s
                }
            }
        }
    }
#pragma unroll
    for (int v = 0; v < 10; ++v) {
        float xv = vs[v];
        for (int off = 32; off; off >>= 1) xv += __shfl_down(xv, off);
        if (lane == 0) wred[w * 16 + v] = xv;
    }
    __syncthreads();
    if (tid < 10) {
        float sum = wred[tid] + wred[16 + tid] + wred[32 + tid] + wred[48 + tid];
        atomicAdd(ssq + tid, sum);
    }
}

// --- final assembly --------------------------------------------------------
__global__ void k_final(const float* __restrict__ vp, const float* __restrict__ vn,
                        const int* __restrict__ counts, const float* __restrict__ ssq,
                        const int* __restrict__ hyper, const int* __restrict__ usemean,
                        const int* __restrict__ use_exp, float* __restrict__ out) {
    __shared__ float red[256];
    __shared__ float rnp[256];
    int tid = threadIdx.x;
    float ck = (float)counts[tid];
    rnp[tid] = ck * (ck - 1.f) * 0.5f;
    __syncthreads();
    for (int off = 128; off; off >>= 1) {
        if (tid < off) rnp[tid] += rnp[tid + off];
        __syncthreads();
    }
    float npos = rnp[0];
    float nneg = 0.5f * (float)N_ROWS * ((float)N_ROWS - 1.f) - npos;

    float accv = 0.f;
    for (int c = tid; c < C_DIM; c += 256) {
        float u = vp[c] / npos - vn[c] / nneg;
        accv += u * u;
    }
    red[tid] = accv;
    __syncthreads();
    for (int off = 128; off; off >>= 1) {
        if (tid < off) red[tid] += red[tid + off];
        __syncthreads();
    }
    if (tid == 0) {
        double S0 = ssq[0], S1 = ssq[1], S2 = ssq[2], R2 = ssq[3], PG = ssq[4];
        double Q2 = ssq[5], TS = ssq[6], PS = ssq[7], GS = ssq[8], SS = ssq[9];
        double Nf = (double)N_ROWS;
        double ni2 = S2 - 2.0 * PG + Q2;
        double nj2 = Nf * Nf * S0 + S2 + SS * SS + Q2 - 2.0 * Nf * S1
                   - 2.0 * Nf * TS + 2.0 * Nf * R2 + 2.0 * PS - 2.0 * PG - 2.0 * GS;
        double trAB = Nf * S1 - S2 - PS + 2.0 * PG - Nf * R2 + GS - Q2;
        double d2 = ni2 - 2.0 * trAB + nj2;
        float norm_i = (float)sqrt(fmax(ni2, 0.0));
        float norm_j = (float)sqrt(fmax(nj2, 0.0));
        float h = (float)hyper[0], um = (float)usemean[0];
        float loss, dist;
        if (use_exp[0]) {
            dist = (float)exp(-sqrt(fmax(d2, 0.0)));
            loss = dist;
        } else {
            float mean_norm = sqrtf((float)C_DIM) * sqrtf(red[0]);
            dist = norm_i - h * norm_j - um * mean_norm;
            loss = fmaxf(dist, 0.f);
        }
        out[0] = loss; out[1] = dist; out[2] = norm_i; out[3] = norm_j;
    }
}

extern "C" void kernel_launch(void* const* d_in, const int* in_sizes, int n_in,
                              void* d_out, int out_size, void* d_ws, size_t ws_size,
                              hipStream_t stream) {
    const float* x = (const float*)d_in[0];
    const int* t = (const int*)d_in[1];
    const int* hyper = (const int*)d_in[2];
    const int* usemean = (const int*)d_in[3];
    const int* use_exp = (const int*)d_in[4];
    float* out = (float*)d_out;

    unsigned char* xbf = (unsigned char*)d_ws;
    size_t xbf_bytes = (size_t)NT * NKC * TILE_B;      // ~17.9 MB
    float* g   = (float*)(xbf + xbf_bytes);            // 256 x 2048
    float* s   = g + (size_t)NCLS * C_DIM;             // 2048
    float* ca  = s + C_DIM;                            // N
    float* cb  = ca + N_ROWS;                          // N
    float* dr  = cb + N_ROWS;                          // N
    float* vp  = dr + N_ROWS;                          // C
    float* vn  = vp + C_DIM;                           // C
    float* ssq = vn + C_DIM;                           // 16
    int* counts  = (int*)(ssq + 16);                   // 256
    int* rowlist = counts + NCLS;                      // 256*64

    // zero atomically-accumulated regions (vp, vn, ssq contiguous)
    hipMemsetAsync(vp, 0, (size_t)(2 * C_DIM + 16) * sizeof(float), stream);

    k_scan<<<1, 256, 0, stream>>>(t, counts, rowlist, ca, cb, dr);
    k_conv_x<<<1024, 256, 0, stream>>>(x, xbf);
    k_classum<<<NCLS, 256, 0, stream>>>(x, counts, rowlist, g);
    k_colsum<<<C_DIM / 256, 256, 0, stream>>>(g, s, C_DIM, NCLS);
    k_conv_ext<<<96, 256, 0, stream>>>(g, s, xbf);
    k_vec<<<dim3(C_DIM / 256, N_ROWS / 256), 256, 0, stream>>>(x, ca, cb, vp, vn,
                                                               N_ROWS, C_DIM);
    k_gram<<<NT * (NT + 1) / 2, 256, 0, stream>>>(xbf, dr, ssq);
    k_final<<<1, 256, 0, stream>>>(vp, vn, counts, ssq, hyper, usemean, use_exp, out);
}

// Round 3
// 232.190 us; speedup vs baseline: 4.4671x; 1.9670x over previous
//
#include <hip/hip_runtime.h>
#include <math.h>

// ---------------------------------------------------------------------------
// xqdaLoss via the N-side Gram. With K = X X^T, Z = class indicator, M = ZZ^T,
// D = diag(c_{t_i}), s = X^T 1, g = Z^T X:
//   T = X^T X, P = X^T D X, G = X^T M X  (never materialized)
//   ||T||^2 = Sum K^2, tr(TP) = Sum d_i K^2, ||P||^2 = Sum d_i d_j K^2
//   tr(TG) = ||X g^T||^2, tr(PG) = Sum_i d_i (X g^T)_i^2, ||G||^2 = ||g g^T||^2
//   s^T T s = ||X s||^2, s^T P s = Sum d_i (Xs)_i^2, s^T G s = Sum_a (g_a . s)^2
// All produced by ONE symmetric bf16 MFMA Gram of A_ext = [X; g; s; 0-pad]
// (4480 x 2048) with a region-aware epilogue -> 10 scalars.
// ---------------------------------------------------------------------------

#define N_ROWS 4096
#define C_DIM  2048
#define NCLS   256
#define RLCAP  64
#define NT     35      // extended 128-row blocks: 32 X + 2 g + 1 (s + pad)
#define NKC    32      // C / 64
#define TILE_B 16384   // tile bytes (128 rows x 64 cols bf16)

typedef __attribute__((ext_vector_type(8))) short short8v;
typedef __attribute__((ext_vector_type(4))) float f32x4;

__device__ __forceinline__ unsigned short f2bf(float f) {
    unsigned u = __float_as_uint(f);
    u += 0x7FFF + ((u >> 16) & 1);   // round-to-nearest-even
    return (unsigned short)(u >> 16);
}

__device__ __forceinline__ void gload16(const void* g, void* l) {
    __builtin_amdgcn_global_load_lds(
        (const __attribute__((address_space(1))) unsigned int*)g,
        (__attribute__((address_space(3))) unsigned int*)l, 16, 0, 0);
}

// swizzled tile byte offset of element (r, c8=col/8): 16B-slot XOR
__device__ __forceinline__ int swz_off(int r, int c8) {
    return r * 128 + ((c8 ^ (r & 7)) << 4);
}

// --- parallel class scan: one wave per class, ballot-based ranks -----------
__global__ __launch_bounds__(64) void k_scan(
    const int* __restrict__ t, int* __restrict__ counts,
    int* __restrict__ rowlist, int* __restrict__ rtmp,
    float* __restrict__ ca, float* __restrict__ cb, float* __restrict__ dr) {
    int a = blockIdx.x;                  // class id
    int lane = threadIdx.x;
    unsigned long long ltmask = (lane == 63) ? ~0ULL >> 1
                                             : ((1ULL << (lane + 1)) - 1) >> 1;
    int base = 0;
    for (int i0 = 0; i0 < N_ROWS; i0 += 64) {
        int i = i0 + lane;
        bool m = (t[i] == a);
        unsigned long long mask = __ballot(m);
        if (m) {
            int r = base + (int)__popcll(mask & ltmask);
            rtmp[i] = r;
            if (r < RLCAP) rowlist[a * RLCAP + r] = i;
        }
        base += (int)__popcll(mask);
    }
    if (lane == 0) counts[a] = base;
    int cnt = base;                      // wave-uniform
    for (int i0 = 0; i0 < N_ROWS; i0 += 64) {
        int i = i0 + lane;
        if (t[i] == a) {
            int r = rtmp[i];
            ca[i] = (float)(2 * r - cnt + 1);
            cb[i] = (float)(2 * i - 2 * r + cnt - N_ROWS);
            dr[i] = (float)cnt;
        }
    }
}

// --- class column-sums g[a][c] (uses row lists) ----------------------------
__global__ void k_classum(const float* __restrict__ x, const int* __restrict__ counts,
                          const int* __restrict__ rowlist, float* __restrict__ g) {
    int a = blockIdx.x, tid = threadIdx.x;
    int cnt = counts[a]; if (cnt > RLCAP) cnt = RLCAP;
    float a0=0,a1=0,a2=0,a3=0,a4=0,a5=0,a6=0,a7=0;
    for (int r = 0; r < cnt; ++r) {
        const float* row = x + (size_t)rowlist[a * RLCAP + r] * C_DIM;
        float4 v0 = *(const float4*)(row + tid * 4);
        float4 v1 = *(const float4*)(row + 1024 + tid * 4);
        a0+=v0.x; a1+=v0.y; a2+=v0.z; a3+=v0.w;
        a4+=v1.x; a5+=v1.y; a6+=v1.z; a7+=v1.w;
    }
    float* go = g + (size_t)a * C_DIM;
    *(float4*)(go + tid * 4) = make_float4(a0,a1,a2,a3);
    *(float4*)(go + 1024 + tid * 4) = make_float4(a4,a5,a6,a7);
}

// --- column totals s_c -----------------------------------------------------
__global__ void k_colsum(const float* __restrict__ g, float* __restrict__ s,
                         int C, int K) {
    int c = blockIdx.x * blockDim.x + threadIdx.x;
    if (c >= C) return;
    float acc = 0.f;
    for (int k = 0; k < K; ++k) acc += g[(size_t)k * C + c];
    s[c] = acc;
}

// --- convert X -> tiled, swizzled bf16 (row blocks 0..31) ------------------
__global__ void k_conv_x(const float* __restrict__ x, unsigned char* __restrict__ xbf) {
    int rb = blockIdx.x >> 5;
    int kc = blockIdx.x & 31;
    unsigned char* tile = xbf + (size_t)(rb * NKC + kc) * TILE_B;
    int t = threadIdx.x;
    int r = t >> 1;
    int half = t & 1;
    const float* src = x + (size_t)(rb * 128 + r) * C_DIM + kc * 64;
#pragma unroll
    for (int u = 0; u < 4; ++u) {
        int c8 = half * 4 + u;
        const float4 v0 = *(const float4*)(src + c8 * 8);
        const float4 v1 = *(const float4*)(src + c8 * 8 + 4);
        int4 w;
        w.x = (int)(f2bf(v0.x) | ((unsigned)f2bf(v0.y) << 16));
        w.y = (int)(f2bf(v0.z) | ((unsigned)f2bf(v0.w) << 16));
        w.z = (int)(f2bf(v1.x) | ((unsigned)f2bf(v1.y) << 16));
        w.w = (int)(f2bf(v1.z) | ((unsigned)f2bf(v1.w) << 16));
        *(int4*)(tile + swz_off(r, c8)) = w;
    }
}

// --- convert extension rows (g, s, zero pad) -> row blocks 32..34 ----------
__global__ void k_conv_ext(const float* __restrict__ g, const float* __restrict__ s,
                           unsigned char* __restrict__ xbf) {
    int bx = blockIdx.x;                 // 0..95
    int rb = 32 + (bx >> 5);
    int kc = bx & 31;
    unsigned char* tile = xbf + (size_t)(rb * NKC + kc) * TILE_B;
    int t = threadIdx.x;
    int r = t >> 1;
    int half = t & 1;
    int grow = rb * 128 + r - N_ROWS;    // 0..383
    const float* src = nullptr;
    if (grow < NCLS)        src = g + (size_t)grow * C_DIM + kc * 64;
    else if (grow == NCLS)  src = s + kc * 64;
#pragma unroll
    for (int u = 0; u < 4; ++u) {
        int c8 = half * 4 + u;
        int4 w = make_int4(0, 0, 0, 0);
        if (src) {
            const float4 v0 = *(const float4*)(src + c8 * 8);
            const float4 v1 = *(const float4*)(src + c8 * 8 + 4);
            w.x = (int)(f2bf(v0.x) | ((unsigned)f2bf(v0.y) << 16));
            w.y = (int)(f2bf(v0.z) | ((unsigned)f2bf(v0.w) << 16));
            w.z = (int)(f2bf(v1.x) | ((unsigned)f2bf(v1.y) << 16));
            w.w = (int)(f2bf(v1.z) | ((unsigned)f2bf(v1.w) << 16));
        }
        *(int4*)(tile + swz_off(r, c8)) = w;
    }
}

// --- vec_pos / vec_neg (X^T a, X^T b) --------------------------------------
__global__ void k_vec(const float* __restrict__ x, const float* __restrict__ ca,
                      const float* __restrict__ cb, float* __restrict__ vp,
                      float* __restrict__ vn, int N, int C) {
    int c = blockIdx.x * blockDim.x + threadIdx.x;
    int i0 = blockIdx.y * 256;
    float ap = 0.f, an = 0.f;
    for (int i = i0; i < i0 + 256; ++i) {
        float xv = x[(size_t)i * C + c];
        ap = fmaf(ca[i], xv, ap);
        an = fmaf(cb[i], xv, an);
    }
    atomicAdd(vp + c, ap);
    atomicAdd(vn + c, an);
}

// --- fragment load: row-major swizzled bf16 tile, both A and B operands ----
__device__ __forceinline__ short8v frag_load(const unsigned char* buf, int rowbase,
                                             int kg, int lane) {
    int row = rowbase + (lane & 15);
    int kgroup = kg + (lane >> 4);
    return *(const short8v*)(buf + row * 128 + (((kgroup ^ (row & 7)) << 4)));
}

// --- extended Gram: MFMA over 128x128 tiles, region-aware epilogue ---------
__global__ __launch_bounds__(256) void k_gram(
    const unsigned char* __restrict__ xbf, const float* __restrict__ dr,
    float* __restrict__ ssq) {
    int b = blockIdx.x, bi = 0;
    while (b >= NT - bi) { b -= NT - bi; ++bi; }
    int bj = bi + b;
    bool diag = (bi == bj);

    __shared__ __align__(16) unsigned char Abuf[TILE_B];
    __shared__ __align__(16) unsigned char Bbuf[TILE_B];
    __shared__ float drow[128], dcol[128];
    __shared__ float wred[4 * 16];

    int tid = threadIdx.x;
    int lane = tid & 63;
    int w = tid >> 6;
    int wr = (w >> 1) * 64;
    int wc = (w & 1) * 64;

    if (tid < 128) {
        int gi = bi * 128 + tid;
        drow[tid] = (gi < N_ROWS) ? dr[gi] : 0.f;
        int gj = bj * 128 + tid;
        dcol[tid] = (gj < N_ROWS) ? dr[gj] : 0.f;
    }

    f32x4 acc[4][4] = {};

    const unsigned char* abase = xbf + (size_t)bi * NKC * TILE_B;
    const unsigned char* bbase = xbf + (size_t)bj * NKC * TILE_B;

    for (int kc = 0; kc < NKC; ++kc) {
        const unsigned char* at = abase + (size_t)kc * TILE_B;
#pragma unroll
        for (int u = 0; u < 4; ++u) {
            int inst = (w << 2) + u;
            gload16(at + inst * 1024 + lane * 16, Abuf + inst * 1024);
        }
        if (!diag) {
            const unsigned char* bt = bbase + (size_t)kc * TILE_B;
#pragma unroll
            for (int u = 0; u < 4; ++u) {
                int inst = (w << 2) + u;
                gload16(bt + inst * 1024 + lane * 16, Bbuf + inst * 1024);
            }
        }
        __syncthreads();
        const unsigned char* bb = diag ? Abuf : Bbuf;
        short8v a[4][2], bfm[4][2];
#pragma unroll
        for (int m = 0; m < 4; ++m)
#pragma unroll
            for (int h = 0; h < 2; ++h) {
                a[m][h]   = frag_load(Abuf, wr + m * 16, h * 4, lane);
                bfm[m][h] = frag_load(bb,   wc + m * 16, h * 4, lane);
            }
#pragma unroll
        for (int m = 0; m < 4; ++m)
#pragma unroll
            for (int n = 0; n < 4; ++n) {
#pragma unroll
                for (int h = 0; h < 2; ++h)
                    acc[m][n] = __builtin_amdgcn_mfma_f32_16x16x32_bf16(
                        a[m][h], bfm[n][h], acc[m][n], 0, 0, 0);
            }
        __syncthreads();
    }

    // epilogue: region-classified weighted square-sums
    float fK = diag ? 1.f : 2.f;
    float vs[10] = {0,0,0,0,0,0,0,0,0,0};
#pragma unroll
    for (int m = 0; m < 4; ++m) {
#pragma unroll
        for (int q = 0; q < 4; ++q) {
            int iw = wr + m * 16 + (lane >> 4) * 4 + q;
            int gi = bi * 128 + iw;
            float di = drow[iw];
            bool iX = gi < N_ROWS;
            bool iG = !iX && (gi < N_ROWS + NCLS);
            bool iS = gi == N_ROWS + NCLS;
#pragma unroll
            for (int n = 0; n < 4; ++n) {
                int jw = wc + n * 16 + (lane & 15);
                int gj = bj * 128 + jw;
                float dj = dcol[jw];
                float k = acc[m][n][q];
                float k2 = k * k;
                bool jX = gj < N_ROWS;
                bool jG = !jX && (gj < N_ROWS + NCLS);
                bool jS = gj == N_ROWS + NCLS;
                if (iX && jX) {
                    vs[0] += fK * k2;                        // Sum K^2
                    vs[1] += 0.5f * fK * (di + dj) * k2;     // Sum d_i K^2
                    vs[2] += fK * di * dj * k2;              // Sum d_i d_j K^2
                } else if (iX && jG) {
                    vs[3] += k2;                             // ||R||^2 = tr(TG)
                    vs[4] += di * k2;                        // tr(PG)
                } else if (iX && jS) {
                    vs[6] += k2;                             // s^T T s
                    vs[7] += di * k2;                        // s^T P s
                } else if (iG && jG) {
                    vs[5] += fK * k2;                        // ||Q||^2 = ||G||^2
                } else if (iG && jS) {
                    vs[8] += k2;                             // s^T G s
                } else if (iS && jS) {
                    vs[9] += k;                              // s^T s
                }
            }
        }
    }
#pragma unroll
    for (int v = 0; v < 10; ++v) {
        float xv = vs[v];
        for (int off = 32; off; off >>= 1) xv += __shfl_down(xv, off);
        if (lane == 0) wred[w * 16 + v] = xv;
    }
    __syncthreads();
    if (tid < 10) {
        float sum = wred[tid] + wred[16 + tid] + wred[32 + tid] + wred[48 + tid];
        atomicAdd(ssq + tid, sum);
    }
}

// --- final assembly --------------------------------------------------------
__global__ void k_final(const float* __restrict__ vp, const float* __restrict__ vn,
                        const int* __restrict__ counts, const float* __restrict__ ssq,
                        const int* __restrict__ hyper, const int* __restrict__ usemean,
                        const int* __restrict__ use_exp, float* __restrict__ out) {
    __shared__ float red[256];
    __shared__ float rnp[256];
    int tid = threadIdx.x;
    float ck = (float)counts[tid];
    rnp[tid] = ck * (ck - 1.f) * 0.5f;
    __syncthreads();
    for (int off = 128; off; off >>= 1) {
        if (tid < off) rnp[tid] += rnp[tid + off];
        __syncthreads();
    }
    float npos = rnp[0];
    float nneg = 0.5f * (float)N_ROWS * ((float)N_ROWS - 1.f) - npos;

    float accv = 0.f;
    for (int c = tid; c < C_DIM; c += 256) {
        float u = vp[c] / npos - vn[c] / nneg;
        accv += u * u;
    }
    red[tid] = accv;
    __syncthreads();
    for (int off = 128; off; off >>= 1) {
        if (tid < off) red[tid] += red[tid + off];
        __syncthreads();
    }
    if (tid == 0) {
        double S0 = ssq[0], S1 = ssq[1], S2 = ssq[2], R2 = ssq[3], PG = ssq[4];
        double Q2 = ssq[5], TS = ssq[6], PS = ssq[7], GS = ssq[8], SS = ssq[9];
        double Nf = (double)N_ROWS;
        double ni2 = S2 - 2.0 * PG + Q2;
        double nj2 = Nf * Nf * S0 + S2 + SS * SS + Q2 - 2.0 * Nf * S1
                   - 2.0 * Nf * TS + 2.0 * Nf * R2 + 2.0 * PS - 2.0 * PG - 2.0 * GS;
        double trAB = Nf * S1 - S2 - PS + 2.0 * PG - Nf * R2 + GS - Q2;
        double d2 = ni2 - 2.0 * trAB + nj2;
        float norm_i = (float)sqrt(fmax(ni2, 0.0));
        float norm_j = (float)sqrt(fmax(nj2, 0.0));
        float h = (float)hyper[0], um = (float)usemean[0];
        float loss, dist;
        if (use_exp[0]) {
            dist = (float)exp(-sqrt(fmax(d2, 0.0)));
            loss = dist;
        } else {
            float mean_norm = sqrtf((float)C_DIM) * sqrtf(red[0]);
            dist = norm_i - h * norm_j - um * mean_norm;
            loss = fmaxf(dist, 0.f);
        }
        out[0] = loss; out[1] = dist; out[2] = norm_i; out[3] = norm_j;
    }
}

extern "C" void kernel_launch(void* const* d_in, const int* in_sizes, int n_in,
                              void* d_out, int out_size, void* d_ws, size_t ws_size,
                              hipStream_t stream) {
    const float* x = (const float*)d_in[0];
    const int* t = (const int*)d_in[1];
    const int* hyper = (const int*)d_in[2];
    const int* usemean = (const int*)d_in[3];
    const int* use_exp = (const int*)d_in[4];
    float* out = (float*)d_out;

    unsigned char* xbf = (unsigned char*)d_ws;
    size_t xbf_bytes = (size_t)NT * NKC * TILE_B;      // ~17.9 MB
    float* g   = (float*)(xbf + xbf_bytes);            // 256 x 2048
    float* s   = g + (size_t)NCLS * C_DIM;             // 2048
    float* ca  = s + C_DIM;                            // N
    float* cb  = ca + N_ROWS;                          // N
    float* dr  = cb + N_ROWS;                          // N
    float* vp  = dr + N_ROWS;                          // C
    float* vn  = vp + C_DIM;                           // C
    float* ssq = vn + C_DIM;                           // 16
    int* counts  = (int*)(ssq + 16);                   // 256
    int* rowlist = counts + NCLS;                      // 256*64
    int* rtmp    = rowlist + NCLS * RLCAP;             // N

    // zero atomically-accumulated regions (vp, vn, ssq contiguous)
    hipMemsetAsync(vp, 0, (size_t)(2 * C_DIM + 16) * sizeof(float), stream);

    k_scan<<<NCLS, 64, 0, stream>>>(t, counts, rowlist, rtmp, ca, cb, dr);
    k_conv_x<<<1024, 256, 0, stream>>>(x, xbf);
    k_classum<<<NCLS, 256, 0, stream>>>(x, counts, rowlist, g);
    k_colsum<<<C_DIM / 256, 256, 0, stream>>>(g, s, C_DIM, NCLS);
    k_conv_ext<<<96, 256, 0, stream>>>(g, s, xbf);
    k_vec<<<dim3(C_DIM / 256, N_ROWS / 256), 256, 0, stream>>>(x, ca, cb, vp, vn,
                                                               N_ROWS, C_DIM);
    k_gram<<<NT * (NT + 1) / 2, 256, 0, stream>>>(xbf, dr, ssq);
    k_final<<<1, 256, 0, stream>>>(vp, vn, counts, ssq, hyper, usemean, use_exp, out);
}

// Round 4
// 126.673 us; speedup vs baseline: 8.1881x; 1.8330x over previous
//
#include <hip/hip_runtime.h>
#include <math.h>

// ---------------------------------------------------------------------------
// xqdaLoss via the N-side Gram. With K = X X^T, Z = class indicator, M = ZZ^T,
// D = diag(c_{t_i}), s = X^T 1, g = Z^T X, u_i = a_i/npos - b_i/nneg:
//   ||T||^2 = Sum K^2, tr(TP) = Sum d_i K^2, ||P||^2 = Sum d_i d_j K^2
//   tr(TG) = ||X g^T||^2, tr(PG) = Sum_i d_i (X g^T)_i^2, ||G||^2 = ||g g^T||^2
//   s^T T s = ||X s||^2, s^T P s = Sum d_i (Xs)_i^2, s^T G s = Sum_a (g_a . s)^2
//   mean-vec norm^2 = u^T K u  (11th invariant, fused into the epilogue)
// ONE symmetric bf16 MFMA Gram of A_ext = [X; g; s; 0-pad] (4480 x 2048),
// double-buffered 2-phase schedule, region-aware epilogue -> 11 scalars.
// ---------------------------------------------------------------------------

#define N_ROWS 4096
#define C_DIM  2048
#define NCLS   256
#define RLCAP  96
#define NT     35      // extended 128-row blocks: 32 X + 2 g + 1 (s + pad)
#define NKC    32      // C / 64
#define TILE_B 16384   // tile bytes (128 rows x 64 cols bf16)

typedef __attribute__((ext_vector_type(8))) short short8v;
typedef __attribute__((ext_vector_type(4))) float f32x4;

__device__ __forceinline__ unsigned short f2bf(float f) {
    unsigned u = __float_as_uint(f);
    u += 0x7FFF + ((u >> 16) & 1);   // round-to-nearest-even
    return (unsigned short)(u >> 16);
}

__device__ __forceinline__ void gload16(const void* g, void* l) {
    __builtin_amdgcn_global_load_lds(
        (const __attribute__((address_space(1))) unsigned int*)g,
        (__attribute__((address_space(3))) unsigned int*)l, 16, 0, 0);
}

// swizzled tile byte offset of element (r, c8=col/8): 16B-slot XOR
__device__ __forceinline__ int swz_off(int r, int c8) {
    return r * 128 + ((c8 ^ (r & 7)) << 4);
}

// --- fused per-class kernel: ballot scan + coeffs + class sums + X->bf16 ---
__global__ __launch_bounds__(256) void k_scan_conv(
    const int* __restrict__ t, const float* __restrict__ x,
    float* __restrict__ g, float* __restrict__ ca, float* __restrict__ cb,
    float* __restrict__ dr, float* __restrict__ nposf,
    unsigned char* __restrict__ xbf) {
    __shared__ int ts[N_ROWS];
    __shared__ int rl[RLCAP];
    __shared__ int cnt_s;
    int a = blockIdx.x, tid = threadIdx.x;
    for (int i = tid; i < N_ROWS; i += 256) ts[i] = t[i];
    __syncthreads();
    if (tid < 64) {
        int lane = tid;
        unsigned long long ltmask = (1ULL << lane) - 1ULL;
        int base = 0;
        for (int i0 = 0; i0 < N_ROWS; i0 += 64) {
            int i = i0 + lane;
            bool m = (ts[i] == a);
            unsigned long long mask = __ballot(m);
            if (m) {
                int r = base + (int)__popcll(mask & ltmask);
                if (r < RLCAP) rl[r] = i;
            }
            base += (int)__popcll(mask);
        }
        if (lane == 0) {
            cnt_s = base;
            float cf = (float)base;
            atomicAdd(nposf, 0.5f * cf * (cf - 1.f));
        }
        int cc = base < RLCAP ? base : RLCAP;
        for (int r = lane; r < cc; r += 64) {
            int i = rl[r];
            ca[i] = (float)(2 * r - base + 1);
            cb[i] = (float)(2 * i - 2 * r + base - N_ROWS);
            dr[i] = (float)base;
        }
    }
    __syncthreads();
    int cnt = cnt_s < RLCAP ? cnt_s : RLCAP;
    // column sums + bf16 swizzled conversion over this class's rows
    int c0 = tid * 4, c1 = 1024 + tid * 4;
    float s0=0,s1=0,s2=0,s3=0,s4=0,s5=0,s6=0,s7=0;
    int kc0 = c0 >> 6, c80 = (c0 & 63) >> 3, sb0 = (c0 & 4) << 1;
    int kc1 = c1 >> 6, c81 = (c1 & 63) >> 3, sb1 = (c1 & 4) << 1;
    for (int r = 0; r < cnt; ++r) {
        int i = rl[r];
        const float* row = x + (size_t)i * C_DIM;
        float4 v0 = *(const float4*)(row + c0);
        float4 v1 = *(const float4*)(row + c1);
        s0+=v0.x; s1+=v0.y; s2+=v0.z; s3+=v0.w;
        s4+=v1.x; s5+=v1.y; s6+=v1.z; s7+=v1.w;
        int rb = i >> 7, rr = i & 127;
        unsigned char* tb = xbf + (size_t)rb * NKC * TILE_B;
        int2 w0, w1;
        w0.x = (int)((unsigned)f2bf(v0.x) | ((unsigned)f2bf(v0.y) << 16));
        w0.y = (int)((unsigned)f2bf(v0.z) | ((unsigned)f2bf(v0.w) << 16));
        w1.x = (int)((unsigned)f2bf(v1.x) | ((unsigned)f2bf(v1.y) << 16));
        w1.y = (int)((unsigned)f2bf(v1.z) | ((unsigned)f2bf(v1.w) << 16));
        *(int2*)(tb + (size_t)kc0 * TILE_B + swz_off(rr, c80) + sb0) = w0;
        *(int2*)(tb + (size_t)kc1 * TILE_B + swz_off(rr, c81) + sb1) = w1;
    }
    float* go = g + (size_t)a * C_DIM;
    *(float4*)(go + c0) = make_float4(s0, s1, s2, s3);
    *(float4*)(go + c1) = make_float4(s4, s5, s6, s7);
}

// --- column totals s_c -----------------------------------------------------
__global__ void k_colsum(const float* __restrict__ g, float* __restrict__ s) {
    int c = blockIdx.x * blockDim.x + threadIdx.x;
    float acc = 0.f;
    for (int k = 0; k < NCLS; ++k) acc += g[(size_t)k * C_DIM + c];
    s[c] = acc;
}

// --- convert extension rows (g, s, zero pad) -> row blocks 32..34 ----------
__global__ void k_conv_ext(const float* __restrict__ g, const float* __restrict__ s,
                           unsigned char* __restrict__ xbf) {
    int bx = blockIdx.x;                 // 0..95
    int rb = 32 + (bx >> 5);
    int kc = bx & 31;
    unsigned char* tile = xbf + (size_t)(rb * NKC + kc) * TILE_B;
    int tid = threadIdx.x;
    int r = tid >> 1;
    int half = tid & 1;
    int grow = rb * 128 + r - N_ROWS;    // 0..383
    const float* src = nullptr;
    if (grow < NCLS)        src = g + (size_t)grow * C_DIM + kc * 64;
    else if (grow == NCLS)  src = s + kc * 64;
#pragma unroll
    for (int u = 0; u < 4; ++u) {
        int c8 = half * 4 + u;
        int4 w = make_int4(0, 0, 0, 0);
        if (src) {
            const float4 v0 = *(const float4*)(src + c8 * 8);
            const float4 v1 = *(const float4*)(src + c8 * 8 + 4);
            w.x = (int)((unsigned)f2bf(v0.x) | ((unsigned)f2bf(v0.y) << 16));
            w.y = (int)((unsigned)f2bf(v0.z) | ((unsigned)f2bf(v0.w) << 16));
            w.z = (int)((unsigned)f2bf(v1.x) | ((unsigned)f2bf(v1.y) << 16));
            w.w = (int)((unsigned)f2bf(v1.z) | ((unsigned)f2bf(v1.w) << 16));
        }
        *(int4*)(tile + swz_off(r, c8)) = w;
    }
}

// --- fragment load: row-major swizzled bf16 tile ---------------------------
__device__ __forceinline__ short8v frag_load(const unsigned char* buf, int rowbase,
                                             int kg, int lane) {
    int row = rowbase + (lane & 15);
    int kgroup = kg + (lane >> 4);
    return *(const short8v*)(buf + row * 128 + ((kgroup ^ (row & 7)) << 4));
}

// --- extended Gram: dbuf 2-phase MFMA, region-aware epilogue ---------------
__global__ __launch_bounds__(256) void k_gram(
    const unsigned char* __restrict__ xbf, const float* __restrict__ dr,
    const float* __restrict__ ca, const float* __restrict__ cb,
    const float* __restrict__ nposf, float* __restrict__ ssq) {
    // bijective XCD-chunked remap of the 630-block triangle grid (m204)
    const int nwg = NT * (NT + 1) / 2;
    int orig = blockIdx.x;
    int q = nwg >> 3, rr = nwg & 7;
    int xcd = orig & 7, loc = orig >> 3;
    int b = (xcd < rr ? xcd * (q + 1) : rr * (q + 1) + (xcd - rr) * q) + loc;
    int bi = 0;
    while (b >= NT - bi) { b -= NT - bi; ++bi; }
    int bj = bi + b;
    bool diag = (bi == bj);

    __shared__ __align__(16) unsigned char Ab[2][TILE_B];
    __shared__ __align__(16) unsigned char Bb[2][TILE_B];
    __shared__ float drow[128], dcol[128], urow[128], ucol[128];
    __shared__ float wred[4 * 16];

    int tid = threadIdx.x;
    int lane = tid & 63;
    int w = tid >> 6;
    int wr = (w >> 1) * 64;
    int wc = (w & 1) * 64;

    const unsigned char* abase = xbf + (size_t)bi * NKC * TILE_B;
    const unsigned char* bbase = xbf + (size_t)bj * NKC * TILE_B;

    // prologue: stage kc=0 into buffer 0
#pragma unroll
    for (int u2 = 0; u2 < 4; ++u2) {
        int inst = (w << 2) + u2;
        gload16(abase + inst * 1024 + lane * 16, Ab[0] + inst * 1024);
    }
    if (!diag) {
#pragma unroll
        for (int u2 = 0; u2 < 4; ++u2) {
            int inst = (w << 2) + u2;
            gload16(bbase + inst * 1024 + lane * 16, Bb[0] + inst * 1024);
        }
    }
    // preamble overlaps the prologue staging latency
    if (tid < 128) {
        float np = nposf[0];
        float inp = 1.f / np;
        float inn = 1.f / (0.5f * (float)N_ROWS * ((float)N_ROWS - 1.f) - np);
        int gi = bi * 128 + tid;
        bool vi = gi < N_ROWS;
        drow[tid] = vi ? dr[gi] : 0.f;
        urow[tid] = vi ? (ca[gi] * inp - cb[gi] * inn) : 0.f;
        int gj = bj * 128 + tid;
        bool vj = gj < N_ROWS;
        dcol[tid] = vj ? dr[gj] : 0.f;
        ucol[tid] = vj ? (ca[gj] * inp - cb[gj] * inn) : 0.f;
    }

    f32x4 acc[4][4] = {};
    __syncthreads();

    int cur = 0;
    for (int kc = 0; kc < NKC; ++kc) {
        if (kc + 1 < NKC) {                       // issue next-tile loads FIRST
            const unsigned char* at = abase + (size_t)(kc + 1) * TILE_B;
#pragma unroll
            for (int u2 = 0; u2 < 4; ++u2) {
                int inst = (w << 2) + u2;
                gload16(at + inst * 1024 + lane * 16, Ab[cur ^ 1] + inst * 1024);
            }
            if (!diag) {
                const unsigned char* bt = bbase + (size_t)(kc + 1) * TILE_B;
#pragma unroll
                for (int u2 = 0; u2 < 4; ++u2) {
                    int inst = (w << 2) + u2;
                    gload16(bt + inst * 1024 + lane * 16, Bb[cur ^ 1] + inst * 1024);
                }
            }
        }
        const unsigned char* ab = Ab[cur];
        const unsigned char* bb = diag ? Ab[cur] : Bb[cur];
        short8v af[4][2], bf[4][2];
#pragma unroll
        for (int m = 0; m < 4; ++m)
#pragma unroll
            for (int h = 0; h < 2; ++h) {
                af[m][h] = frag_load(ab, wr + m * 16, h * 4, lane);
                bf[m][h] = frag_load(bb, wc + m * 16, h * 4, lane);
            }
#pragma unroll
        for (int m = 0; m < 4; ++m)
#pragma unroll
            for (int n = 0; n < 4; ++n)
#pragma unroll
                for (int h = 0; h < 2; ++h)
                    acc[m][n] = __builtin_amdgcn_mfma_f32_16x16x32_bf16(
                        af[m][h], bf[n][h], acc[m][n], 0, 0, 0);
        __syncthreads();                          // drains vmcnt -> next buf ready
        cur ^= 1;
    }

    // epilogue: region-classified weighted square-sums (11 invariants)
    float fK = diag ? 1.f : 2.f;
    float vs[11] = {0,0,0,0,0,0,0,0,0,0,0};
#pragma unroll
    for (int m = 0; m < 4; ++m) {
#pragma unroll
        for (int qq = 0; qq < 4; ++qq) {
            int iw = wr + m * 16 + (lane >> 4) * 4 + qq;
            int gi = bi * 128 + iw;
            float di = drow[iw];
            float ui = urow[iw];
            bool iX = gi < N_ROWS;
            bool iG = !iX && (gi < N_ROWS + NCLS);
            bool iS = gi == N_ROWS + NCLS;
#pragma unroll
            for (int n = 0; n < 4; ++n) {
                int jw = wc + n * 16 + (lane & 15);
                int gj = bj * 128 + jw;
                float dj = dcol[jw];
                float k = acc[m][n][qq];
                float k2 = k * k;
                bool jX = gj < N_ROWS;
                bool jG = !jX && (gj < N_ROWS + NCLS);
                bool jS = gj == N_ROWS + NCLS;
                if (iX && jX) {
                    vs[0] += fK * k2;                        // Sum K^2
                    vs[1] += 0.5f * fK * (di + dj) * k2;     // Sum d_i K^2
                    vs[2] += fK * di * dj * k2;              // Sum d_i d_j K^2
                    vs[10] += fK * ui * ucol[jw] * k;        // u^T K u
                } else if (iX && jG) {
                    vs[3] += k2;                             // tr(TG)
                    vs[4] += di * k2;                        // tr(PG)
                } else if (iX && jS) {
                    vs[6] += k2;                             // s^T T s
                    vs[7] += di * k2;                        // s^T P s
                } else if (iG && jG) {
                    vs[5] += fK * k2;                        // ||G||^2
                } else if (iG && jS) {
                    vs[8] += k2;                             // s^T G s
                } else if (iS && jS) {
                    vs[9] += k;                              // s^T s
                }
            }
        }
    }
#pragma unroll
    for (int v = 0; v < 11; ++v) {
        float xv = vs[v];
        for (int off = 32; off; off >>= 1) xv += __shfl_down(xv, off);
        if (lane == 0) wred[w * 16 + v] = xv;
    }
    __syncthreads();
    if (tid < 11) {
        float sum = wred[tid] + wred[16 + tid] + wred[32 + tid] + wred[48 + tid];
        atomicAdd(ssq + tid, sum);
    }
}

// --- final assembly --------------------------------------------------------
__global__ void k_final(const float* __restrict__ ssq, const float* __restrict__ nposf,
                        const int* __restrict__ hyper, const int* __restrict__ usemean,
                        const int* __restrict__ use_exp, float* __restrict__ out) {
    if (threadIdx.x != 0) return;
    double S0 = ssq[0], S1 = ssq[1], S2 = ssq[2], R2 = ssq[3], PG = ssq[4];
    double Q2 = ssq[5], TS = ssq[6], PS = ssq[7], GS = ssq[8], SS = ssq[9];
    double U2 = ssq[10];
    double Nf = (double)N_ROWS;
    double ni2 = S2 - 2.0 * PG + Q2;
    double nj2 = Nf * Nf * S0 + S2 + SS * SS + Q2 - 2.0 * Nf * S1
               - 2.0 * Nf * TS + 2.0 * Nf * R2 + 2.0 * PS - 2.0 * PG - 2.0 * GS;
    double trAB = Nf * S1 - S2 - PS + 2.0 * PG - Nf * R2 + GS - Q2;
    double d2 = ni2 - 2.0 * trAB + nj2;
    float norm_i = (float)sqrt(fmax(ni2, 0.0));
    float norm_j = (float)sqrt(fmax(nj2, 0.0));
    float h = (float)hyper[0], um = (float)usemean[0];
    float loss, dist;
    if (use_exp[0]) {
        dist = (float)exp(-sqrt(fmax(d2, 0.0)));
        loss = dist;
    } else {
        float mean_norm = sqrtf((float)C_DIM) * sqrtf(fmaxf((float)U2, 0.f));
        dist = norm_i - h * norm_j - um * mean_norm;
        loss = fmaxf(dist, 0.f);
    }
    out[0] = loss; out[1] = dist; out[2] = norm_i; out[3] = norm_j;
}

extern "C" void kernel_launch(void* const* d_in, const int* in_sizes, int n_in,
                              void* d_out, int out_size, void* d_ws, size_t ws_size,
                              hipStream_t stream) {
    const float* x = (const float*)d_in[0];
    const int* t = (const int*)d_in[1];
    const int* hyper = (const int*)d_in[2];
    const int* usemean = (const int*)d_in[3];
    const int* use_exp = (const int*)d_in[4];
    float* out = (float*)d_out;

    unsigned char* xbf = (unsigned char*)d_ws;
    size_t xbf_bytes = (size_t)NT * NKC * TILE_B;      // ~18.4 MB
    float* g     = (float*)(xbf + xbf_bytes);          // 256 x 2048
    float* s     = g + (size_t)NCLS * C_DIM;           // 2048
    float* ca    = s + C_DIM;                          // N
    float* cb    = ca + N_ROWS;                        // N
    float* dr    = cb + N_ROWS;                        // N
    float* ssq   = dr + N_ROWS;                        // 16
    float* nposf = ssq + 16;                           // 1

    // zero atomically-accumulated scalars (ssq + nposf contiguous)
    hipMemsetAsync(ssq, 0, 32 * sizeof(float), stream);

    k_scan_conv<<<NCLS, 256, 0, stream>>>(t, x, g, ca, cb, dr, nposf, xbf);
    k_colsum<<<C_DIM / 256, 256, 0, stream>>>(g, s);
    k_conv_ext<<<96, 256, 0, stream>>>(g, s, xbf);
    k_gram<<<NT * (NT + 1) / 2, 256, 0, stream>>>(xbf, dr, ca, cb, nposf, ssq);
    k_final<<<1, 64, 0, stream>>>(ssq, nposf, hyper, usemean, use_exp, out);
}